// Round 1
// baseline (518.949 us; speedup 1.0000x reference)
//
#include <hip/hip_runtime.h>
#include <math.h>

namespace {

constexpr int kC  = 200;   // channels
constexpr int kD  = 800;   // 4*C
constexpr int kS  = 25;    // seq
constexpr int kH  = 32;    // hidden
constexpr int kNC = 16;    // classes
constexpr int kR  = 8;     // rows per block
constexpr int kLS = 904;   // padded LDS row stride (floats) for hs/zb

// chunk m (4 floats, m=0..199) stored at float offset 4m + 4*(m/8)
// => 16B pad every 128B so strided chunk reads spread across banks.
__device__ __forceinline__ int choff(int m) { return 4*m + 4*(m >> 3); }

__device__ __forceinline__ float4 ld4s(const float* p) { return *(const float4*)p; }
__device__ __forceinline__ void   st4s(float* p, float4 v) { *(float4*)p = v; }

__device__ __forceinline__ float4 f4fma(float s, float4 w, float4 a) {
    a.x = fmaf(s, w.x, a.x); a.y = fmaf(s, w.y, a.y);
    a.z = fmaf(s, w.z, a.z); a.w = fmaf(s, w.w, a.w);
    return a;
}

// LayerNorm of one 800-elem row (in LDS, chunk-padded layout) by 32 lanes.
// Lane j owns chunks j+32k (k=0..5) + tail scalar at d=768+j (offset 864+j).
// Writes normalized row into orow (same layout). Two-pass (matches reference).
__device__ __forceinline__ void layernorm_row(const float* hrow, float* orow,
                                              const float* __restrict__ g,
                                              const float* __restrict__ b, int j)
{
    float4 v4[6]; float vt;
    float sm = 0.f;
    #pragma unroll
    for (int k = 0; k < 6; ++k) {
        v4[k] = ld4s(&hrow[choff(j + 32*k)]);
        sm += (v4[k].x + v4[k].y) + (v4[k].z + v4[k].w);
    }
    vt = hrow[864 + j];
    sm += vt;
    #pragma unroll
    for (int mk = 16; mk >= 1; mk >>= 1) sm += __shfl_xor(sm, mk, 64);
    const float mean = sm * (1.0f/800.0f);
    float ssq = 0.f;
    #pragma unroll
    for (int k = 0; k < 6; ++k) {
        float a = v4[k].x - mean, bq = v4[k].y - mean;
        float c = v4[k].z - mean, dq = v4[k].w - mean;
        ssq += a*a + bq*bq + c*c + dq*dq;
    }
    { float a = vt - mean; ssq += a*a; }
    #pragma unroll
    for (int mk = 16; mk >= 1; mk >>= 1) ssq += __shfl_xor(ssq, mk, 64);
    const float rstd = rsqrtf(ssq*(1.0f/800.0f) + 1e-5f);
    #pragma unroll
    for (int k = 0; k < 6; ++k) {
        const int d0 = 4*(j + 32*k);
        float4 g4 = ld4s(&g[d0]);
        float4 b4 = ld4s(&b[d0]);
        float4 y;
        y.x = (v4[k].x - mean)*rstd*g4.x + b4.x;
        y.y = (v4[k].y - mean)*rstd*g4.y + b4.y;
        y.z = (v4[k].z - mean)*rstd*g4.z + b4.z;
        y.w = (v4[k].w - mean)*rstd*g4.w + b4.w;
        st4s(&orow[choff(j + 32*k)], y);
    }
    orow[864 + j] = (vt - mean)*rstd*g[768 + j] + b[768 + j];
}

__global__ __launch_bounds__(256, 2)
void essp_kernel(const float* __restrict__ x,
                 const float* __restrict__ lnA_g, const float* __restrict__ lnA_b,
                 const float* __restrict__ lnB_g, const float* __restrict__ lnB_b,
                 const float* __restrict__ w1, const float* __restrict__ b1,
                 const float* __restrict__ w2, const float* __restrict__ b2,
                 const float* __restrict__ fc_w, const float* __restrict__ fc_b,
                 float* __restrict__ out, int Btot)
{
    __shared__ float hs[kR*kLS];      // residual state h, 8 rows
    __shared__ float zb[kR*kLS];      // y/z buffer; reused as mm1 partials; reused as pooled
    __shared__ float vb[kR*36];       // gelu outputs (padded stride 36)
    __shared__ float ub[2*kR*kNC];    // final fc partials

    const int t   = threadIdx.x;
    const int b0  = blockIdx.x * kR;
    const int grp = t >> 5;           // row group 0..7
    const int j   = t & 31;           // lane in group

    // ---------------- phase 1: h = [min, mean, last, max] per channel ----------------
    if (t < kC) {
        const int c = t;
        for (int r = 0; r < kR; ++r) {
            if (b0 + r >= Btot) break;
            const float* xp = x + (size_t)(b0 + r) * (kS*kC) + c;
            float v0 = xp[0];
            float mn = v0, mx = v0, sm = v0;
            #pragma unroll
            for (int s = 1; s < kS-1; ++s) {
                float v = xp[s*kC];
                mn = fminf(mn, v); mx = fmaxf(mx, v); sm += v;
            }
            float last = xp[(kS-1)*kC];
            st4s(&hs[r*kLS + choff(c)], make_float4(mn, sm*(1.0f/24.0f), last, mx));
        }
    }
    __syncthreads();

    // ---------------- 2 transformer-ish layers ----------------
    for (int layer = 0; layer < 2; ++layer) {
        const float* gA  = lnA_g + layer*kD;
        const float* bAv = lnA_b + layer*kD;
        const float* gB  = lnB_g + layer*kD;
        const float* bBv = lnB_b + layer*kD;
        const float* w1p = w1 + layer*kD*kH;
        const float* b1p = b1 + layer*kH;
        const float* w2p = w2 + layer*kH*kD;
        const float* b2p = b2 + layer*kD;

        // ---- LN_A -> y (zb)
        layernorm_row(&hs[grp*kLS], &zb[grp*kLS], gA, bAv, j);
        __syncthreads();

        // ---- h += sppcf(y)
        {
            float* yr = &zb[grp*kLS];
            float* hr = &hs[grp*kLS];
            #pragma unroll
            for (int k2 = 0; k2 < 7; ++k2) {
                const int c = j + 32*k2;
                if (c < kC) {
                    float4 y4 = ld4s(&yr[choff(c)]);
                    const int kk = (c <= 196) ? c : c - 4;   // f2 tail maps to p16[c-4]
                    float s16 = 0.f;
                    #pragma unroll
                    for (int q = 0; q < 4; ++q) {
                        float4 w = ld4s(&yr[choff(kk + q)]);
                        s16 += (w.x + w.y) + (w.z + w.w);
                    }
                    float4 h4 = ld4s(&hr[choff(c)]);
                    h4.x += (y4.x + y4.y) * 0.5f;
                    h4.y += (y4.x + y4.y + y4.z + y4.w) * 0.25f;
                    h4.z += (y4.z + y4.w) * 0.5f;
                    h4.w += s16 * (1.0f/16.0f);
                    st4s(&hr[choff(c)], h4);
                }
            }
        }
        __syncthreads();

        // ---- LN_B -> z (zb)
        layernorm_row(&hs[grp*kLS], &zb[grp*kLS], gB, bBv, j);
        __syncthreads();

        // ---- mm1: u[r][h] = z[r]@w1  (weights read once per block, used for 8 rows)
        // t<200: cg = t&7 -> cols 4cg..4cg+3 ; dg = t>>3 (<25) -> d-range [32dg, 32dg+32)
        float4 acc[kR];
        const int cg = t & 7, dg = t >> 3;
        if (t < 200) {
            #pragma unroll
            for (int r = 0; r < kR; ++r) acc[r] = make_float4(0.f,0.f,0.f,0.f);
            for (int cc = 0; cc < 8; ++cc) {
                const int m  = dg*8 + cc;
                const int d0 = 4*m;
                float4 wr0 = ld4s(&w1p[(d0+0)*kH + 4*cg]);
                float4 wr1 = ld4s(&w1p[(d0+1)*kH + 4*cg]);
                float4 wr2 = ld4s(&w1p[(d0+2)*kH + 4*cg]);
                float4 wr3 = ld4s(&w1p[(d0+3)*kH + 4*cg]);
                #pragma unroll
                for (int r = 0; r < kR; ++r) {
                    float4 z4 = ld4s(&zb[r*kLS + choff(m)]);
                    acc[r] = f4fma(z4.x, wr0, acc[r]);
                    acc[r] = f4fma(z4.y, wr1, acc[r]);
                    acc[r] = f4fma(z4.z, wr2, acc[r]);
                    acc[r] = f4fma(z4.w, wr3, acc[r]);
                }
            }
        }
        __syncthreads();   // everyone done READING zb
        if (t < 200) {
            #pragma unroll
            for (int r = 0; r < kR; ++r)
                st4s(&zb[(r*25 + dg)*36 + 4*cg], acc[r]);   // partials into dead zb
        }
        __syncthreads();

        // ---- reduce partials + bias + exact GELU -> vb
        {
            const int r = grp, h = j;
            float u = b1p[h];
            #pragma unroll
            for (int dg2 = 0; dg2 < 25; ++dg2)
                u += zb[(r*25 + dg2)*36 + h];
            vb[r*36 + h] = 0.5f*u*(1.0f + erff(u*0.70710678118654752f));
        }
        __syncthreads();

        // ---- mm2: h[r][d] += v[r]@w2 + b2   (w2 rows deduped across the 8 r-lanes)
        // t<200: r2 = t&7 ; ds = t>>3 (<25) -> d-range [32ds, 32ds+32)
        if (t < 200) {
            const int r2 = t & 7, ds = t >> 3;
            float vv[kH];
            #pragma unroll
            for (int h4i = 0; h4i < 8; ++h4i) {
                float4 v = ld4s(&vb[r2*36 + 4*h4i]);
                vv[4*h4i+0] = v.x; vv[4*h4i+1] = v.y;
                vv[4*h4i+2] = v.z; vv[4*h4i+3] = v.w;
            }
            #pragma unroll
            for (int c4 = 0; c4 < 8; ++c4) {
                const int d0 = ds*32 + 4*c4;
                float4 a0 = make_float4(0.f,0.f,0.f,0.f);
                float4 a1 = make_float4(0.f,0.f,0.f,0.f);
                #pragma unroll
                for (int h = 0; h < kH; h += 2) {
                    float4 wA = ld4s(&w2p[(h+0)*kD + d0]);
                    float4 wB = ld4s(&w2p[(h+1)*kD + d0]);
                    a0 = f4fma(vv[h+0], wA, a0);
                    a1 = f4fma(vv[h+1], wB, a1);
                }
                float4 bb = ld4s(&b2p[d0]);
                const int m = ds*8 + c4;
                float4 hv = ld4s(&hs[r2*kLS + choff(m)]);
                hv.x += a0.x + a1.x + bb.x;
                hv.y += a0.y + a1.y + bb.y;
                hv.z += a0.z + a1.z + bb.z;
                hv.w += a0.w + a1.w + bb.w;
                st4s(&hs[r2*kLS + choff(m)], hv);
            }
        }
        __syncthreads();
    }

    // ---------------- pooled = mean4(h) ; out = pooled @ fc_w + fc_b ----------------
    {
        // pooled into zb (plain layout [r*kC + c])
        float* hr = &hs[grp*kLS];
        #pragma unroll
        for (int k2 = 0; k2 < 7; ++k2) {
            const int c = j + 32*k2;
            if (c < kC) {
                float4 h4 = ld4s(&hr[choff(c)]);
                zb[grp*kC + c] = (h4.x + h4.y + h4.z + h4.w) * 0.25f;
            }
        }
    }
    __syncthreads();
    {
        const int n = t & 15, r = (t >> 4) & 7, dup = t >> 7;  // 16n x 8r x 2dup
        const int c0 = dup * 100;
        float acc = 0.f;
        #pragma unroll 4
        for (int c = c0; c < c0 + 100; ++c)
            acc += zb[r*kC + c] * fc_w[c*kNC + n];
        ub[(dup*kR + r)*kNC + n] = acc;
    }
    __syncthreads();
    if (t < 128) {
        const int n = t & 15, r = t >> 4;
        if (b0 + r < Btot) {
            float o = ub[r*kNC + n] + ub[(kR + r)*kNC + n] + fc_b[n];
            out[(size_t)(b0 + r)*kNC + n] = o;
        }
    }
}

} // namespace

extern "C" void kernel_launch(void* const* d_in, const int* in_sizes, int n_in,
                              void* d_out, int out_size, void* d_ws, size_t ws_size,
                              hipStream_t stream) {
    const float* x     = (const float*)d_in[0];
    const float* lnA_g = (const float*)d_in[1];
    const float* lnA_b = (const float*)d_in[2];
    const float* lnB_g = (const float*)d_in[3];
    const float* lnB_b = (const float*)d_in[4];
    const float* w1    = (const float*)d_in[5];
    const float* b1    = (const float*)d_in[6];
    const float* w2    = (const float*)d_in[7];
    const float* b2    = (const float*)d_in[8];
    const float* fc_w  = (const float*)d_in[9];
    const float* fc_b  = (const float*)d_in[10];
    float* out = (float*)d_out;

    const int Btot   = in_sizes[0] / (kS * kC);
    const int blocks = (Btot + kR - 1) / kR;

    hipLaunchKernelGGL(essp_kernel, dim3(blocks), dim3(256), 0, stream,
                       x, lnA_g, lnA_b, lnB_g, lnB_b, w1, b1, w2, b2,
                       fc_w, fc_b, out, Btot);
}

// Round 2
// 353.246 us; speedup vs baseline: 1.4691x; 1.4691x over previous
//
#include <hip/hip_runtime.h>
#include <math.h>

namespace {

constexpr int kC  = 200;   // channels
constexpr int kD  = 800;   // 4*C
constexpr int kS  = 25;    // seq
constexpr int kH  = 32;    // hidden
constexpr int kNC = 16;    // classes
constexpr int kR  = 4;     // rows per block (one wave per row)
constexpr int kRW = 800;   // LDS row stride in words (no pad; XOR swizzle instead)

// word offset of chunk m (4 floats) within a row: XOR-swizzle bank spreading.
// word = 4m ^ ((m>>3 & 7)<<2). Bijective (flips word bits 2-4 by a function of
// higher bits), keeps 16B alignment.
__device__ __forceinline__ int woff(int m) { return (m << 2) ^ ((m & 0x38) >> 1); }

__device__ __forceinline__ float4 ld4(const float* p) { return *(const float4*)p; }
__device__ __forceinline__ void   st4(float* p, float4 v) { *(float4*)p = v; }
__device__ __forceinline__ float  hsum4(float4 v) { return (v.x + v.y) + (v.z + v.w); }

__device__ __forceinline__ float4 f4fma(float s, float4 w, float4 a) {
    a.x = fmaf(s, w.x, a.x); a.y = fmaf(s, w.y, a.y);
    a.z = fmaf(s, w.z, a.z); a.w = fmaf(s, w.w, a.w);
    return a;
}

// Intra-wave LDS fence: wave-local RAW through LDS only needs lgkmcnt(0)
// (all lanes of the wave issued the write in the same instruction).
__device__ __forceinline__ void wfence() {
    asm volatile("s_waitcnt lgkmcnt(0)" ::: "memory");
}

// LayerNorm of one 800-elem LDS row by one full wave (lane j owns chunks
// j, j+64, j+128, and lanes 0..7 own 192+j). Two-pass, writes y to yrow.
__device__ __forceinline__ void ln_row(const float* hrow, float* yrow,
                                       const float* __restrict__ g,
                                       const float* __restrict__ bb, int j)
{
    const bool tail = (j < 8);
    float4 v0 = ld4(&hrow[woff(j)]);
    float4 v1 = ld4(&hrow[woff(j + 64)]);
    float4 v2 = ld4(&hrow[woff(j + 128)]);
    float4 v3 = make_float4(0.f, 0.f, 0.f, 0.f);
    if (tail) v3 = ld4(&hrow[woff(192 + j)]);

    float sm = hsum4(v0) + hsum4(v1) + hsum4(v2) + hsum4(v3);
    #pragma unroll
    for (int mk = 32; mk >= 1; mk >>= 1) sm += __shfl_xor(sm, mk, 64);
    const float mean = sm * (1.0f / 800.0f);

    float ssq = 0.f;
    { float a=v0.x-mean,b=v0.y-mean,c=v0.z-mean,d=v0.w-mean; ssq += a*a+b*b+c*c+d*d; }
    { float a=v1.x-mean,b=v1.y-mean,c=v1.z-mean,d=v1.w-mean; ssq += a*a+b*b+c*c+d*d; }
    { float a=v2.x-mean,b=v2.y-mean,c=v2.z-mean,d=v2.w-mean; ssq += a*a+b*b+c*c+d*d; }
    if (tail) { float a=v3.x-mean,b=v3.y-mean,c=v3.z-mean,d=v3.w-mean; ssq += a*a+b*b+c*c+d*d; }
    #pragma unroll
    for (int mk = 32; mk >= 1; mk >>= 1) ssq += __shfl_xor(ssq, mk, 64);
    const float rstd = rsqrtf(ssq * (1.0f / 800.0f) + 1e-5f);

    auto stc = [&](int m, float4 v) {
        float4 g4 = ld4(&g[4 * m]);
        float4 b4 = ld4(&bb[4 * m]);
        float4 y;
        y.x = (v.x - mean) * rstd * g4.x + b4.x;
        y.y = (v.y - mean) * rstd * g4.y + b4.y;
        y.z = (v.z - mean) * rstd * g4.z + b4.z;
        y.w = (v.w - mean) * rstd * g4.w + b4.w;
        st4(&yrow[woff(m)], y);
    };
    stc(j, v0); stc(j + 64, v1); stc(j + 128, v2);
    if (tail) stc(192 + j, v3);
}

// h += sppcf(y); wave-local (lane j owns same chunks as ln_row).
__device__ __forceinline__ void sppcf_add(const float* yrow, float* hrow, int j)
{
    auto one = [&](int m) {
        const int kk = (m <= 196) ? m : m - 4;          // f2 tail -> p16[m-4]
        float4 q0 = ld4(&yrow[woff(kk)]);
        float4 q1 = ld4(&yrow[woff(kk + 1)]);
        float4 q2 = ld4(&yrow[woff(kk + 2)]);
        float4 q3 = ld4(&yrow[woff(kk + 3)]);
        float4 y4 = (m <= 196) ? q0 : ld4(&yrow[woff(m)]);
        const float s16 = hsum4(q0) + hsum4(q1) + hsum4(q2) + hsum4(q3);
        float4 h4 = ld4(&hrow[woff(m)]);
        h4.x += (y4.x + y4.y) * 0.5f;
        h4.y += (y4.x + y4.y + y4.z + y4.w) * 0.25f;
        h4.z += (y4.z + y4.w) * 0.5f;
        h4.w += s16 * (1.0f / 16.0f);
        st4(&hrow[woff(m)], h4);
    };
    one(j); one(j + 64); one(j + 128);
    if (j < 8) one(192 + j);
}

__global__ __launch_bounds__(256, 6)
void essp_kernel(const float* __restrict__ x,
                 const float* __restrict__ lnA_g, const float* __restrict__ lnA_b,
                 const float* __restrict__ lnB_g, const float* __restrict__ lnB_b,
                 const float* __restrict__ w1, const float* __restrict__ b1,
                 const float* __restrict__ w2, const float* __restrict__ b2,
                 const float* __restrict__ fc_w, const float* __restrict__ fc_b,
                 float* __restrict__ out, int Btot)
{
    __shared__ float hs[kR * kRW];   // residual state h (4 rows, swizzled chunks)
    __shared__ float zb[kR * kRW];   // y/z buffer; mm1 partials; pooled
    __shared__ float vb[kR * kH];    // gelu outputs

    const int t   = threadIdx.x;
    const int w   = t >> 6;          // wave id = local row
    const int j   = t & 63;          // lane
    const int b0  = blockIdx.x * kR;
    const int row = b0 + w;

    // ---- featurize: h = interleaved [min, mean(24), last, max] per channel ----
    if (j < 50 && row < Btot) {
        const float* xp = x + (size_t)row * (kS * kC) + j * 4;
        float4 v = ld4(xp);
        float4 mn = v, mx = v, sm = v;
        #pragma unroll 8
        for (int s = 1; s < kS - 1; ++s) {
            float4 u = ld4(xp + s * kC);
            mn.x = fminf(mn.x, u.x); mx.x = fmaxf(mx.x, u.x); sm.x += u.x;
            mn.y = fminf(mn.y, u.y); mx.y = fmaxf(mx.y, u.y); sm.y += u.y;
            mn.z = fminf(mn.z, u.z); mx.z = fmaxf(mx.z, u.z); sm.z += u.z;
            mn.w = fminf(mn.w, u.w); mx.w = fmaxf(mx.w, u.w); sm.w += u.w;
        }
        float4 last = ld4(xp + (kS - 1) * kC);
        const float i24 = 1.0f / 24.0f;
        float* hr = &hs[w * kRW];
        st4(&hr[woff(4 * j + 0)], make_float4(mn.x, sm.x * i24, last.x, mx.x));
        st4(&hr[woff(4 * j + 1)], make_float4(mn.y, sm.y * i24, last.y, mx.y));
        st4(&hr[woff(4 * j + 2)], make_float4(mn.z, sm.z * i24, last.z, mx.z));
        st4(&hr[woff(4 * j + 3)], make_float4(mn.w, sm.w * i24, last.w, mx.w));
    }
    wfence();

    for (int layer = 0; layer < 2; ++layer) {
        const float* gA  = lnA_g + layer * kD;
        const float* bAv = lnA_b + layer * kD;
        const float* gB  = lnB_g + layer * kD;
        const float* bBv = lnB_b + layer * kD;
        const float* w1p = w1 + layer * kD * kH;
        const float* b1p = b1 + layer * kH;
        const float* w2p = w2 + layer * kH * kD;
        const float* b2p = b2 + layer * kD;

        // ---- row-local chain (no block barrier needed between these) ----
        ln_row(&hs[w * kRW], &zb[w * kRW], gA, bAv, j);
        wfence();
        sppcf_add(&zb[w * kRW], &hs[w * kRW], j);
        wfence();
        ln_row(&hs[w * kRW], &zb[w * kRW], gB, bBv, j);
        __syncthreads();                       // mm1 reads all rows' z

        // ---- mm1: u = z @ w1, 4-row register amortization ----
        // thread (dg<25, cg<8): d-range [32dg,32dg+32), h-quad 4cg..4cg+3
        float4 acc0 = make_float4(0,0,0,0), acc1 = acc0, acc2 = acc0, acc3 = acc0;
        const int dg = t >> 3, cg = t & 7;
        if (t < 200) {
            #pragma unroll
            for (int cc = 0; cc < 8; ++cc) {
                const int m = dg * 8 + cc, d0 = 4 * m;
                float4 wr0 = ld4(&w1p[(d0 + 0) * kH + 4 * cg]);
                float4 wr1 = ld4(&w1p[(d0 + 1) * kH + 4 * cg]);
                float4 wr2 = ld4(&w1p[(d0 + 2) * kH + 4 * cg]);
                float4 wr3 = ld4(&w1p[(d0 + 3) * kH + 4 * cg]);
                float4 z0 = ld4(&zb[0 * kRW + woff(m)]);
                float4 z1 = ld4(&zb[1 * kRW + woff(m)]);
                float4 z2 = ld4(&zb[2 * kRW + woff(m)]);
                float4 z3 = ld4(&zb[3 * kRW + woff(m)]);
                acc0 = f4fma(z0.x, wr0, acc0); acc0 = f4fma(z0.y, wr1, acc0);
                acc0 = f4fma(z0.z, wr2, acc0); acc0 = f4fma(z0.w, wr3, acc0);
                acc1 = f4fma(z1.x, wr0, acc1); acc1 = f4fma(z1.y, wr1, acc1);
                acc1 = f4fma(z1.z, wr2, acc1); acc1 = f4fma(z1.w, wr3, acc1);
                acc2 = f4fma(z2.x, wr0, acc2); acc2 = f4fma(z2.y, wr1, acc2);
                acc2 = f4fma(z2.z, wr2, acc2); acc2 = f4fma(z2.w, wr3, acc2);
                acc3 = f4fma(z3.x, wr0, acc3); acc3 = f4fma(z3.y, wr1, acc3);
                acc3 = f4fma(z3.z, wr2, acc3); acc3 = f4fma(z3.w, wr3, acc3);
            }
        }
        __syncthreads();                       // everyone done reading zb
        if (t < 200) {
            // partials into dead zb, swizzled: word(r,dg,h) = r*800+dg*32+(h^((dg&7)<<2))
            const int pb = dg * 32 + ((4 * cg) ^ ((dg & 7) << 2));
            st4(&zb[0 * kRW + pb], acc0);
            st4(&zb[1 * kRW + pb], acc1);
            st4(&zb[2 * kRW + pb], acc2);
            st4(&zb[3 * kRW + pb], acc3);
        }
        __syncthreads();

        // ---- reduce partials + bias + exact GELU -> vb ----
        if (t < 128) {
            const int r = t >> 5, h = t & 31;
            float u = b1p[h];
            #pragma unroll
            for (int dq = 0; dq < 25; ++dq)
                u += zb[r * kRW + dq * 32 + (h ^ ((dq & 7) << 2))];
            vb[r * kH + h] = 0.5f * u * (1.0f + erff(u * 0.70710678118654752440f));
        }
        __syncthreads();

        // ---- mm2: h += v @ w2 + b2 ----
        // thread (r2 = t&3, ds = t>>2 < 50): 16 d's = chunks 4ds..4ds+3 of row r2
        if (t < 200) {
            const int r2 = t & 3, ds = t >> 2;
            float4 a0 = make_float4(0,0,0,0), a1 = a0, a2 = a0, a3 = a0;
            #pragma unroll
            for (int hc = 0; hc < 8; ++hc) {
                float4 vq = ld4(&vb[r2 * kH + 4 * hc]);
                #pragma unroll
                for (int hh = 0; hh < 4; ++hh) {
                    const float s = (hh == 0) ? vq.x : (hh == 1) ? vq.y
                                  : (hh == 2) ? vq.z : vq.w;
                    const float* wr = &w2p[(4 * hc + hh) * kD + ds * 16];
                    a0 = f4fma(s, ld4(wr + 0),  a0);
                    a1 = f4fma(s, ld4(wr + 4),  a1);
                    a2 = f4fma(s, ld4(wr + 8),  a2);
                    a3 = f4fma(s, ld4(wr + 12), a3);
                }
            }
            const int m0 = ds * 4;
            float* hr = &hs[r2 * kRW];
            { float4 bq = ld4(&b2p[4*(m0+0)]); float4 h4 = ld4(&hr[woff(m0+0)]);
              h4.x += a0.x+bq.x; h4.y += a0.y+bq.y; h4.z += a0.z+bq.z; h4.w += a0.w+bq.w;
              st4(&hr[woff(m0+0)], h4); }
            { float4 bq = ld4(&b2p[4*(m0+1)]); float4 h4 = ld4(&hr[woff(m0+1)]);
              h4.x += a1.x+bq.x; h4.y += a1.y+bq.y; h4.z += a1.z+bq.z; h4.w += a1.w+bq.w;
              st4(&hr[woff(m0+1)], h4); }
            { float4 bq = ld4(&b2p[4*(m0+2)]); float4 h4 = ld4(&hr[woff(m0+2)]);
              h4.x += a2.x+bq.x; h4.y += a2.y+bq.y; h4.z += a2.z+bq.z; h4.w += a2.w+bq.w;
              st4(&hr[woff(m0+2)], h4); }
            { float4 bq = ld4(&b2p[4*(m0+3)]); float4 h4 = ld4(&hr[woff(m0+3)]);
              h4.x += a3.x+bq.x; h4.y += a3.y+bq.y; h4.z += a3.z+bq.z; h4.w += a3.w+bq.w;
              st4(&hr[woff(m0+3)], h4); }
        }
        __syncthreads();                        // next phase reads hs cross-thread
    }

    // ---- pooled = mean4(h) (wave-local, into dead zb, plain layout) ----
    {
        const float* hr = &hs[w * kRW];
        float* pr = &zb[w * kRW];
        pr[j]       = hsum4(ld4(&hr[woff(j)]))       * 0.25f;
        pr[j + 64]  = hsum4(ld4(&hr[woff(j + 64)]))  * 0.25f;
        pr[j + 128] = hsum4(ld4(&hr[woff(j + 128)])) * 0.25f;
        if (j < 8) pr[192 + j] = hsum4(ld4(&hr[woff(192 + j)])) * 0.25f;
    }
    wfence();

    // ---- out = pooled @ fc_w + fc_b (wave-local; shfl reduce over 4 segments) ----
    {
        const int n = j & 15, sg = j >> 4;
        const float* pr = &zb[w * kRW + sg * 50];
        const float* fw = fc_w + (size_t)(sg * 50) * kNC + n;
        float acc = 0.f;
        #pragma unroll 10
        for (int i = 0; i < 50; ++i) acc += pr[i] * fw[i * kNC];
        acc += __shfl_xor(acc, 16, 64);
        acc += __shfl_xor(acc, 32, 64);
        if (j < kNC && row < Btot)
            out[(size_t)row * kNC + j] = acc + fc_b[j];
    }
}

} // namespace

extern "C" void kernel_launch(void* const* d_in, const int* in_sizes, int n_in,
                              void* d_out, int out_size, void* d_ws, size_t ws_size,
                              hipStream_t stream) {
    const float* x     = (const float*)d_in[0];
    const float* lnA_g = (const float*)d_in[1];
    const float* lnA_b = (const float*)d_in[2];
    const float* lnB_g = (const float*)d_in[3];
    const float* lnB_b = (const float*)d_in[4];
    const float* w1    = (const float*)d_in[5];
    const float* b1    = (const float*)d_in[6];
    const float* w2    = (const float*)d_in[7];
    const float* b2    = (const float*)d_in[8];
    const float* fc_w  = (const float*)d_in[9];
    const float* fc_b  = (const float*)d_in[10];
    float* out = (float*)d_out;

    const int Btot   = in_sizes[0] / (kS * kC);
    const int blocks = (Btot + kR - 1) / kR;

    hipLaunchKernelGGL(essp_kernel, dim3(blocks), dim3(256), 0, stream,
                       x, lnA_g, lnA_b, lnB_g, lnB_b, w1, b1, w2, b2,
                       fc_w, fc_b, out, Btot);
}

// Round 4
// 241.846 us; speedup vs baseline: 2.1458x; 1.4606x over previous
//
#include <hip/hip_runtime.h>
#include <math.h>

namespace {

constexpr int kC  = 200;   // channels
constexpr int kD  = 800;   // 4*C
constexpr int kS  = 25;    // seq
constexpr int kH  = 32;    // hidden
constexpr int kNC = 16;    // classes
constexpr int kR  = 4;     // rows per block (one wave per row)
constexpr int kRW = 800;   // LDS row stride in words (no pad; XOR swizzle instead)

typedef float vfloat4 __attribute__((ext_vector_type(4)));  // native clang vec

// word offset of chunk m (4 floats) within a row: XOR-swizzle bank spreading.
__device__ __forceinline__ int woff(int m) { return (m << 2) ^ ((m & 0x38) >> 1); }

__device__ __forceinline__ float4 ld4(const float* p) { return *(const float4*)p; }
__device__ __forceinline__ float4 ld4nt(const float* p) {
    vfloat4 v = __builtin_nontemporal_load((const vfloat4*)p);
    return make_float4(v.x, v.y, v.z, v.w);
}
__device__ __forceinline__ void   st4(float* p, float4 v) { *(float4*)p = v; }
__device__ __forceinline__ float  hsum4(float4 v) { return (v.x + v.y) + (v.z + v.w); }

__device__ __forceinline__ float4 f4fma(float s, float4 w, float4 a) {
    a.x = fmaf(s, w.x, a.x); a.y = fmaf(s, w.y, a.y);
    a.z = fmaf(s, w.z, a.z); a.w = fmaf(s, w.w, a.w);
    return a;
}

// Intra-wave LDS fence: wave-local RAW through LDS only needs lgkmcnt(0).
__device__ __forceinline__ void wfence() {
    asm volatile("s_waitcnt lgkmcnt(0)" ::: "memory");
}

// LayerNorm of one 800-elem LDS row by one full wave (lane j owns chunks
// j, j+64, j+128, and lanes 0..7 own 192+j). Two-pass, writes y to yrow.
__device__ __forceinline__ void ln_row(const float* hrow, float* yrow,
                                       const float* __restrict__ g,
                                       const float* __restrict__ bb, int j)
{
    const bool tail = (j < 8);
    float4 v0 = ld4(&hrow[woff(j)]);
    float4 v1 = ld4(&hrow[woff(j + 64)]);
    float4 v2 = ld4(&hrow[woff(j + 128)]);
    float4 v3 = make_float4(0.f, 0.f, 0.f, 0.f);
    if (tail) v3 = ld4(&hrow[woff(192 + j)]);

    float sm = hsum4(v0) + hsum4(v1) + hsum4(v2) + hsum4(v3);
    #pragma unroll
    for (int mk = 32; mk >= 1; mk >>= 1) sm += __shfl_xor(sm, mk, 64);
    const float mean = sm * (1.0f / 800.0f);

    float ssq = 0.f;
    { float a=v0.x-mean,b=v0.y-mean,c=v0.z-mean,d=v0.w-mean; ssq += a*a+b*b+c*c+d*d; }
    { float a=v1.x-mean,b=v1.y-mean,c=v1.z-mean,d=v1.w-mean; ssq += a*a+b*b+c*c+d*d; }
    { float a=v2.x-mean,b=v2.y-mean,c=v2.z-mean,d=v2.w-mean; ssq += a*a+b*b+c*c+d*d; }
    if (tail) { float a=v3.x-mean,b=v3.y-mean,c=v3.z-mean,d=v3.w-mean; ssq += a*a+b*b+c*c+d*d; }
    #pragma unroll
    for (int mk = 32; mk >= 1; mk >>= 1) ssq += __shfl_xor(ssq, mk, 64);
    const float rstd = rsqrtf(ssq * (1.0f / 800.0f) + 1e-5f);

    auto stc = [&](int m, float4 v) {
        float4 g4 = ld4(&g[4 * m]);
        float4 b4 = ld4(&bb[4 * m]);
        float4 y;
        y.x = (v.x - mean) * rstd * g4.x + b4.x;
        y.y = (v.y - mean) * rstd * g4.y + b4.y;
        y.z = (v.z - mean) * rstd * g4.z + b4.z;
        y.w = (v.w - mean) * rstd * g4.w + b4.w;
        st4(&yrow[woff(m)], y);
    };
    stc(j, v0); stc(j + 64, v1); stc(j + 128, v2);
    if (tail) stc(192 + j, v3);
}

// h += sppcf(y); wave-local (lane j owns same chunks as ln_row).
__device__ __forceinline__ void sppcf_add(const float* yrow, float* hrow, int j)
{
    auto one = [&](int m) {
        const int kk = (m <= 196) ? m : m - 4;          // f2 tail -> p16[m-4]
        float4 q0 = ld4(&yrow[woff(kk)]);
        float4 q1 = ld4(&yrow[woff(kk + 1)]);
        float4 q2 = ld4(&yrow[woff(kk + 2)]);
        float4 q3 = ld4(&yrow[woff(kk + 3)]);
        float4 y4 = (m <= 196) ? q0 : ld4(&yrow[woff(m)]);
        const float s16 = hsum4(q0) + hsum4(q1) + hsum4(q2) + hsum4(q3);
        float4 h4 = ld4(&hrow[woff(m)]);
        h4.x += (y4.x + y4.y) * 0.5f;
        h4.y += (y4.x + y4.y + y4.z + y4.w) * 0.25f;
        h4.z += (y4.z + y4.w) * 0.5f;
        h4.w += s16 * (1.0f / 16.0f);
        st4(&hrow[woff(m)], h4);
    };
    one(j); one(j + 64); one(j + 128);
    if (j < 8) one(192 + j);
}

__global__ __launch_bounds__(256, 4)
void essp_kernel(const float* __restrict__ x,
                 const float* __restrict__ lnA_g, const float* __restrict__ lnA_b,
                 const float* __restrict__ lnB_g, const float* __restrict__ lnB_b,
                 const float* __restrict__ w1, const float* __restrict__ b1,
                 const float* __restrict__ w2, const float* __restrict__ b2,
                 const float* __restrict__ fc_w, const float* __restrict__ fc_b,
                 float* __restrict__ out, int Btot)
{
    __shared__ float hs[kR * kRW];   // residual state h (4 rows, swizzled chunks)
    __shared__ float zb[kR * kRW];   // y/z buffer; mm1 partials; pooled
    __shared__ float vb[kR * kH];    // gelu outputs

    const int t   = threadIdx.x;
    const int w   = t >> 6;          // wave id = local row
    const int j   = t & 63;          // lane
    const int b0  = blockIdx.x * kR;
    const int row = b0 + w;

    // ---- featurize: h = interleaved [min, mean(24), last, max] per channel ----
    if (j < 50 && row < Btot) {
        const float* xp = x + (size_t)row * (kS * kC) + j * 4;
        float4 v = ld4nt(xp);
        float4 mn = v, mx = v, sm = v;
        #pragma unroll
        for (int s = 1; s < kS - 1; ++s) {
            float4 u = ld4nt(xp + s * kC);
            mn.x = fminf(mn.x, u.x); mx.x = fmaxf(mx.x, u.x); sm.x += u.x;
            mn.y = fminf(mn.y, u.y); mx.y = fmaxf(mx.y, u.y); sm.y += u.y;
            mn.z = fminf(mn.z, u.z); mx.z = fmaxf(mx.z, u.z); sm.z += u.z;
            mn.w = fminf(mn.w, u.w); mx.w = fmaxf(mx.w, u.w); sm.w += u.w;
        }
        float4 last = ld4nt(xp + (kS - 1) * kC);
        const float i24 = 1.0f / 24.0f;
        float* hr = &hs[w * kRW];
        st4(&hr[woff(4 * j + 0)], make_float4(mn.x, sm.x * i24, last.x, mx.x));
        st4(&hr[woff(4 * j + 1)], make_float4(mn.y, sm.y * i24, last.y, mx.y));
        st4(&hr[woff(4 * j + 2)], make_float4(mn.z, sm.z * i24, last.z, mx.z));
        st4(&hr[woff(4 * j + 3)], make_float4(mn.w, sm.w * i24, last.w, mx.w));
    }
    wfence();

    for (int layer = 0; layer < 2; ++layer) {
        const float* gA  = lnA_g + layer * kD;
        const float* bAv = lnA_b + layer * kD;
        const float* gB  = lnB_g + layer * kD;
        const float* bBv = lnB_b + layer * kD;
        const float* w1p = w1 + layer * kD * kH;
        const float* b1p = b1 + layer * kH;
        const float* w2p = w2 + layer * kH * kD;
        const float* b2p = b2 + layer * kD;

        // ---- row-local chain (wave-synchronous, no block barrier) ----
        ln_row(&hs[w * kRW], &zb[w * kRW], gA, bAv, j);
        wfence();
        sppcf_add(&zb[w * kRW], &hs[w * kRW], j);
        wfence();
        ln_row(&hs[w * kRW], &zb[w * kRW], gB, bBv, j);
        __syncthreads();                       // mm1 reads all rows' z

        // ---- mm1: u = z @ w1, 4-row register amortization ----
        // thread (dg<25, cg<8): d-range [32dg,32dg+32), h-quad 4cg..4cg+3
        float4 acc0 = make_float4(0,0,0,0), acc1 = acc0, acc2 = acc0, acc3 = acc0;
        const int dg = t >> 3, cg = t & 7;
        if (t < 200) {
            #pragma unroll
            for (int cc = 0; cc < 8; ++cc) {
                const int m = dg * 8 + cc, d0 = 4 * m;
                float4 wr0 = ld4(&w1p[(d0 + 0) * kH + 4 * cg]);
                float4 wr1 = ld4(&w1p[(d0 + 1) * kH + 4 * cg]);
                float4 wr2 = ld4(&w1p[(d0 + 2) * kH + 4 * cg]);
                float4 wr3 = ld4(&w1p[(d0 + 3) * kH + 4 * cg]);
                float4 z0 = ld4(&zb[0 * kRW + woff(m)]);
                float4 z1 = ld4(&zb[1 * kRW + woff(m)]);
                float4 z2 = ld4(&zb[2 * kRW + woff(m)]);
                float4 z3 = ld4(&zb[3 * kRW + woff(m)]);
                acc0 = f4fma(z0.x, wr0, acc0); acc0 = f4fma(z0.y, wr1, acc0);
                acc0 = f4fma(z0.z, wr2, acc0); acc0 = f4fma(z0.w, wr3, acc0);
                acc1 = f4fma(z1.x, wr0, acc1); acc1 = f4fma(z1.y, wr1, acc1);
                acc1 = f4fma(z1.z, wr2, acc1); acc1 = f4fma(z1.w, wr3, acc1);
                acc2 = f4fma(z2.x, wr0, acc2); acc2 = f4fma(z2.y, wr1, acc2);
                acc2 = f4fma(z2.z, wr2, acc2); acc2 = f4fma(z2.w, wr3, acc2);
                acc3 = f4fma(z3.x, wr0, acc3); acc3 = f4fma(z3.y, wr1, acc3);
                acc3 = f4fma(z3.z, wr2, acc3); acc3 = f4fma(z3.w, wr3, acc3);
            }
        }
        __syncthreads();                       // everyone done reading zb
        if (t < 200) {
            // partials into dead zb, swizzled: word(r,dg,h) = r*800+dg*32+(h^((dg&7)<<2))
            const int pb = dg * 32 + ((4 * cg) ^ ((dg & 7) << 2));
            st4(&zb[0 * kRW + pb], acc0);
            st4(&zb[1 * kRW + pb], acc1);
            st4(&zb[2 * kRW + pb], acc2);
            st4(&zb[3 * kRW + pb], acc3);
        }
        __syncthreads();

        // ---- reduce partials + bias + exact GELU -> vb ----
        if (t < 128) {
            const int r = t >> 5, h = t & 31;
            float u = b1p[h];
            #pragma unroll
            for (int dq = 0; dq < 25; ++dq)
                u += zb[r * kRW + dq * 32 + (h ^ ((dq & 7) << 2))];
            vb[r * kH + h] = 0.5f * u * (1.0f + erff(u * 0.70710678118654752440f));
        }
        __syncthreads();

        // ---- mm2: h += v @ w2 + b2, chunk-stationary (w2 read ONCE per block) ----
        // thread t<200 owns chunk m=t (d = 4t..4t+3) for ALL 4 rows.
        if (t < 200) {
            float4 a0 = make_float4(0,0,0,0), a1 = a0, a2 = a0, a3 = a0;
            #pragma unroll
            for (int hc = 0; hc < 8; ++hc) {
                float4 wq0 = ld4(&w2p[(4*hc + 0) * kD + 4*t]);
                float4 wq1 = ld4(&w2p[(4*hc + 1) * kD + 4*t]);
                float4 wq2 = ld4(&w2p[(4*hc + 2) * kD + 4*t]);
                float4 wq3 = ld4(&w2p[(4*hc + 3) * kD + 4*t]);
                float4 vq;
                vq = ld4(&vb[0 * kH + 4*hc]);
                a0 = f4fma(vq.x, wq0, a0); a0 = f4fma(vq.y, wq1, a0);
                a0 = f4fma(vq.z, wq2, a0); a0 = f4fma(vq.w, wq3, a0);
                vq = ld4(&vb[1 * kH + 4*hc]);
                a1 = f4fma(vq.x, wq0, a1); a1 = f4fma(vq.y, wq1, a1);
                a1 = f4fma(vq.z, wq2, a1); a1 = f4fma(vq.w, wq3, a1);
                vq = ld4(&vb[2 * kH + 4*hc]);
                a2 = f4fma(vq.x, wq0, a2); a2 = f4fma(vq.y, wq1, a2);
                a2 = f4fma(vq.z, wq2, a2); a2 = f4fma(vq.w, wq3, a2);
                vq = ld4(&vb[3 * kH + 4*hc]);
                a3 = f4fma(vq.x, wq0, a3); a3 = f4fma(vq.y, wq1, a3);
                a3 = f4fma(vq.z, wq2, a3); a3 = f4fma(vq.w, wq3, a3);
            }
            const float4 bq = ld4(&b2p[4*t]);
            const int wo = woff(t);
            { float4 h4 = ld4(&hs[0*kRW + wo]);
              h4.x += a0.x+bq.x; h4.y += a0.y+bq.y; h4.z += a0.z+bq.z; h4.w += a0.w+bq.w;
              st4(&hs[0*kRW + wo], h4); }
            { float4 h4 = ld4(&hs[1*kRW + wo]);
              h4.x += a1.x+bq.x; h4.y += a1.y+bq.y; h4.z += a1.z+bq.z; h4.w += a1.w+bq.w;
              st4(&hs[1*kRW + wo], h4); }
            { float4 h4 = ld4(&hs[2*kRW + wo]);
              h4.x += a2.x+bq.x; h4.y += a2.y+bq.y; h4.z += a2.z+bq.z; h4.w += a2.w+bq.w;
              st4(&hs[2*kRW + wo], h4); }
            { float4 h4 = ld4(&hs[3*kRW + wo]);
              h4.x += a3.x+bq.x; h4.y += a3.y+bq.y; h4.z += a3.z+bq.z; h4.w += a3.w+bq.w;
              st4(&hs[3*kRW + wo], h4); }
        }
        __syncthreads();                        // next phase reads hs cross-thread
    }

    // ---- pooled = mean4(h) (wave-local, into dead zb, plain layout) ----
    {
        const float* hr = &hs[w * kRW];
        float* pr = &zb[w * kRW];
        pr[j]       = hsum4(ld4(&hr[woff(j)]))       * 0.25f;
        pr[j + 64]  = hsum4(ld4(&hr[woff(j + 64)]))  * 0.25f;
        pr[j + 128] = hsum4(ld4(&hr[woff(j + 128)])) * 0.25f;
        if (j < 8) pr[192 + j] = hsum4(ld4(&hr[woff(192 + j)])) * 0.25f;
    }
    wfence();

    // ---- out = pooled @ fc_w + fc_b (wave-local; shfl reduce over 4 segments) ----
    {
        const int n = j & 15, sg = j >> 4;
        const float* pr = &zb[w * kRW + sg * 50];
        const float* fw = fc_w + (size_t)(sg * 50) * kNC + n;
        float acc = 0.f;
        #pragma unroll 10
        for (int i = 0; i < 50; ++i) acc += pr[i] * fw[i * kNC];
        acc += __shfl_xor(acc, 16, 64);
        acc += __shfl_xor(acc, 32, 64);
        if (j < kNC && row < Btot)
            out[(size_t)row * kNC + j] = acc + fc_b[j];
    }
}

} // namespace

extern "C" void kernel_launch(void* const* d_in, const int* in_sizes, int n_in,
                              void* d_out, int out_size, void* d_ws, size_t ws_size,
                              hipStream_t stream) {
    const float* x     = (const float*)d_in[0];
    const float* lnA_g = (const float*)d_in[1];
    const float* lnA_b = (const float*)d_in[2];
    const float* lnB_g = (const float*)d_in[3];
    const float* lnB_b = (const float*)d_in[4];
    const float* w1    = (const float*)d_in[5];
    const float* b1    = (const float*)d_in[6];
    const float* w2    = (const float*)d_in[7];
    const float* b2    = (const float*)d_in[8];
    const float* fc_w  = (const float*)d_in[9];
    const float* fc_b  = (const float*)d_in[10];
    float* out = (float*)d_out;

    const int Btot   = in_sizes[0] / (kS * kC);
    const int blocks = (Btot + kR - 1) / kR;

    hipLaunchKernelGGL(essp_kernel, dim3(blocks), dim3(256), 0, stream,
                       x, lnA_g, lnA_b, lnB_g, lnB_b, w1, b1, w2, b2,
                       fc_w, fc_b, out, Btot);
}